// Round 1
// 889.849 us; speedup vs baseline: 1.1218x; 1.1218x over previous
//
#include <hip/hip_runtime.h>
#include <hip/hip_bf16.h>

// B=2, N=1024, D=512, H=8, DH=64, HD=512, FF=2048, DEPTH=4.
// Dual-dtype IO (bf16 or fp32, runtime-detected from ln1_g word0).
// bf16 MFMA 16x16x32 everywhere, fp32 accum, fp32 residual chain.
// Scores: BD scatter-stored (rel_shift, injective, diag = zero set) into Scb;
// fused kernel: AC mfma (8 h-planes in regs) + Scb add + softmax-over-h -> attn.
// R1: vectorized prep_weights (exact grid, 16B loads/stores), vectorized
//     cast_in/cast_out/rcat_all, wsum hoisted+batched over all 4 layers.

using bf16 = __hip_bfloat16;
typedef __attribute__((ext_vector_type(8))) short short8;
typedef __attribute__((ext_vector_type(4))) float float4v;
typedef __attribute__((ext_vector_type(2))) unsigned int uint2v;

__device__ __forceinline__ float ldsel(const void* p, long long i, bool isbf) {
    return isbf ? __bfloat162float(((const bf16*)p)[i]) : ((const float*)p)[i];
}
__device__ __forceinline__ void stsel(void* p, long long i, bool isbf, float v) {
    if (isbf) ((bf16*)p)[i] = __float2bfloat16(v);
    else      ((float*)p)[i] = v;
}
__device__ __forceinline__ float bf2f(short u) {
    return __uint_as_float(((unsigned)(unsigned short)u) << 16);
}
__device__ __forceinline__ short f2bf(float f) {
    bf16 h = __float2bfloat16(f);
    return *reinterpret_cast<short*>(&h);
}

__global__ void detect_kernel(const unsigned int* __restrict__ g, int* __restrict__ flag) {
    if (threadIdx.x == 0) flag[0] = ((g[0] & 0xFFFFu) != 0u) ? 1 : 0;
}

// 8 elements per thread. n8 = total/8.
__global__ __launch_bounds__(256) void cast_in(const void* __restrict__ in, float* __restrict__ out,
                                               int n8, const int* __restrict__ flagp) {
    bool bf = flagp[0] != 0;
    int i = blockIdx.x * 256 + threadIdx.x;
    if (i >= n8) return;
    long long b = (long long)i * 8;
    if (bf) {
        short8 v = *(const short8*)((const bf16*)in + b);
        float4v o0, o1;
        #pragma unroll
        for (int j = 0; j < 4; ++j) { o0[j] = bf2f(v[j]); o1[j] = bf2f(v[4 + j]); }
        *(float4v*)(out + b) = o0;
        *(float4v*)(out + b + 4) = o1;
    } else {
        float4v a0 = *(const float4v*)((const float*)in + b);
        float4v a1 = *(const float4v*)((const float*)in + b + 4);
        *(float4v*)(out + b) = a0;
        *(float4v*)(out + b + 4) = a1;
    }
}
__global__ __launch_bounds__(256) void cast_out(const float* __restrict__ in, void* __restrict__ out,
                                                int n8, const int* __restrict__ flagp) {
    bool bf = flagp[0] != 0;
    int i = blockIdx.x * 256 + threadIdx.x;
    if (i >= n8) return;
    long long b = (long long)i * 8;
    float4v a0 = *(const float4v*)(in + b);
    float4v a1 = *(const float4v*)(in + b + 4);
    if (bf) {
        short8 v;
        #pragma unroll
        for (int j = 0; j < 4; ++j) { v[j] = f2bf(a0[j]); v[4 + j] = f2bf(a1[j]); }
        *(short8*)((bf16*)out + b) = v;
    } else {
        *(float4v*)((float*)out + b) = a0;
        *(float4v*)((float*)out + b + 4) = a1;
    }
}

// rcat[m, s*512+k] = r_s[m,k], s = blockIdx.y. 8 elems/thread.
__global__ __launch_bounds__(256) void rcat_all(const void* __restrict__ r0, const void* __restrict__ r1,
                                                const void* __restrict__ r2, bf16* __restrict__ dst,
                                                const int* __restrict__ flagp) {
    bool bf = flagp[0] != 0;
    int s = blockIdx.y;
    const void* src = (s == 0) ? r0 : ((s == 1) ? r1 : r2);
    int i = blockIdx.x * 256 + threadIdx.x;   // 0..131071 (1M/8)
    int m = i >> 6, k8 = (i & 63) * 8;
    long long b = (long long)m * 512 + k8;
    short8 v;
    if (bf) {
        v = *(const short8*)((const bf16*)src + b);
    } else {
        float4v a0 = *(const float4v*)((const float*)src + b);
        float4v a1 = *(const float4v*)((const float*)src + b + 4);
        #pragma unroll
        for (int j = 0; j < 4; ++j) { v[j] = f2bf(a0[j]); v[4 + j] = f2bf(a1[j]); }
    }
    *(short8*)(dst + (size_t)m * 1536 + s * 512 + k8) = v;
}

// ---- all weight transposes (all 4 layers) in ONE exact-sized dispatch ----
// 3840 blocks: 960 per layer: [0,192) qkvT | [192,448) wcat0..2,outT (64 each)
//              | [448,704) ff1T | [704,960) ff2T. 64x64 tile per block.
__global__ __launch_bounds__(256) void prep_weights(
    const void* __restrict__ s0, const void* __restrict__ s1, const void* __restrict__ s2,
    const void* __restrict__ s3, const void* __restrict__ s4, const void* __restrict__ s5,
    const void* __restrict__ s6, bf16* __restrict__ arena,
    const int* __restrict__ flagp) {
    const bool bf = flagp[0] != 0;
    const int bid = blockIdx.x;
    const int l = bid / 960;
    const int rem = bid - l * 960;
    const int LW = 3932160;
    const int L = l * LW;

    int j, tile, tx, ldi, ldo;
    long long ioff;
    int dstoff;
    if (rem < 192)      { j = 0; tile = rem;                tx = 24; ldi = 1536; ldo = 512;
                          ioff = (long long)l * 786432;  dstoff = L; }
    else if (rem < 448) { j = 1 + ((rem - 192) >> 6); tile = (rem - 192) & 63; tx = 8; ldi = 512;
                          ioff = (long long)l * 262144;
                          if (j <= 3) { ldo = 1536; dstoff = L + 786432 + (j - 1) * 512; }
                          else        { ldo = 512;  dstoff = L + 1572864; } }
    else if (rem < 704) { j = 5; tile = rem - 448;          tx = 32; ldi = 2048; ldo = 512;
                          ioff = (long long)l * 1048576; dstoff = L + 1835008; }
    else                { j = 6; tile = rem - 704;          tx = 8;  ldi = 512;  ldo = 2048;
                          ioff = (long long)l * 1048576; dstoff = L + 2883584; }
    const void* in = (j == 0) ? s0 : (j == 1) ? s1 : (j == 2) ? s2 :
                     (j == 3) ? s3 : (j == 4) ? s4 : (j == 5) ? s5 : s6;
    bf16* out = arena + dstoff;
    const int bx = tile % tx, by = tile / tx;
    const int n0 = bx * 64, k0 = by * 64;
    const int tid = threadIdx.x;

    // t[rr][cc] = in[k0+rr][n0+cc] (bf16)
    __shared__ bf16 t[64][72];

    if (bf) {
        const bf16* inb = (const bf16*)in + ioff;
        #pragma unroll
        for (int p = 0; p < 2; ++p) {
            int e = tid + p * 256;
            int r = e >> 3, c = (e & 7) * 8;
            *(uint4*)&t[r][c] = *(const uint4*)(inb + (size_t)(k0 + r) * ldi + n0 + c);
        }
    } else {
        const float* inf = (const float*)in + ioff;
        #pragma unroll
        for (int p = 0; p < 4; ++p) {
            int e = tid + p * 256;
            int r = e >> 4, c = (e & 15) * 4;
            float4v v = *(const float4v*)(inf + (size_t)(k0 + r) * ldi + n0 + c);
            union { bf16 h[4]; uint2v u; } w;
            #pragma unroll
            for (int q = 0; q < 4; ++q) w.h[q] = __float2bfloat16(v[q]);
            *reinterpret_cast<uint2v*>(&t[r][c]) = w.u;
        }
    }
    __syncthreads();
    // out[(n0+r)*ldo + k0+c] = t[c][r]; 8 scalar LDS reads -> one 16B store.
    #pragma unroll
    for (int p = 0; p < 2; ++p) {
        int e = tid + p * 256;
        int r = e >> 3, c = (e & 7) * 8;
        union { short8 s; uint4 u; } o;
        #pragma unroll
        for (int q = 0; q < 8; ++q)
            o.s[q] = *reinterpret_cast<const short*>(&t[c + q][r]);
        *(uint4*)(out + (size_t)(n0 + r) * ldo + k0 + c) = o.u;
    }
}

// ---- layernorm: one block per row, D=512; fp32 in -> bf16 out ----
__global__ __launch_bounds__(256) void ln_kernel(const float* __restrict__ x,
                                                 const void* __restrict__ g, long long goff,
                                                 const void* __restrict__ bta, long long boff,
                                                 bf16* __restrict__ out,
                                                 const int* __restrict__ flagp) {
    bool bf = flagp[0] != 0;
    int row = blockIdx.x;
    const float* xr = x + (size_t)row * 512;
    int tid = threadIdx.x;
    float v0 = xr[tid], v1 = xr[tid + 256];
    float s = v0 + v1, q = v0 * v0 + v1 * v1;
    #pragma unroll
    for (int off = 32; off; off >>= 1) {
        s += __shfl_down(s, off);
        q += __shfl_down(q, off);
    }
    __shared__ float ls[4], lq[4];
    int wid = tid >> 6, lane = tid & 63;
    if (lane == 0) { ls[wid] = s; lq[wid] = q; }
    __syncthreads();
    if (tid == 0) {
        float ts = ls[0] + ls[1] + ls[2] + ls[3];
        float tq = lq[0] + lq[1] + lq[2] + lq[3];
        float m = ts * (1.f / 512.f);
        float var = tq * (1.f / 512.f) - m * m;
        ls[0] = m; lq[0] = rsqrtf(var + 1e-5f);
    }
    __syncthreads();
    float m = ls[0], r = lq[0];
    out[(size_t)row * 512 + tid] =
        __float2bfloat16((v0 - m) * r * ldsel(g, goff + tid, bf) + ldsel(bta, boff + tid, bf));
    out[(size_t)row * 512 + tid + 256] =
        __float2bfloat16((v1 - m) * r * ldsel(g, goff + tid + 256, bf) + ldsel(bta, boff + tid + 256, bf));
}

// ---- MFMA GEMM: C[m,n] = sum_k A[m,k]*B[n,k] (NT). 128x64 tile, BK=32. ----
// 4 waves (2x2): wave tile 64x32 = 4x2 frags of 16x16x32.
// EPI: 1 qkv (n<512: +bias_pf; n<1024: k; else vT scatter); 2 fp32 +bias+resid;
//      3 bf16 gelu(+bias); 4 rel-shift scatter-store v/3; 5 bf16 plain store.
template<int EPI>
__global__ __launch_bounds__(256) void mgemm(
    const bf16* __restrict__ A, int lda, long long sAb, long long sAh,
    const bf16* __restrict__ B, int ldb, long long sBb, long long sBh,
    void* __restrict__ Cv, int ldc, long long sCb, long long sCh,
    int K,
    const void* __restrict__ bias, long long biasoff,
    float* __restrict__ resid,
    bf16* __restrict__ aux,
    const int* __restrict__ flagp) {
    const bool flg = flagp[0] != 0;
    const int tid = threadIdx.x;
    const int lane = tid & 63, wave = tid >> 6;
    const int m0 = blockIdx.y * 128, n0 = blockIdx.x * 64;
    const int zb = (int)(blockIdx.z >> 3), zh = (int)(blockIdx.z & 7);
    A += (size_t)zb * sAb + (size_t)zh * sAh;
    B += (size_t)zb * sBb + (size_t)zh * sBh;

    __shared__ bf16 As[128][40];
    __shared__ bf16 Bs[64][40];

    const int ar = tid >> 2, ak = (tid & 3) * 8;
    const bf16* Ap0 = A + (size_t)(m0 + ar) * lda + ak;
    const bf16* Ap1 = Ap0 + (size_t)64 * lda;
    const bf16* Bp  = B + (size_t)(n0 + ar) * ldb + ak;

    const int wm = (wave >> 1) * 64, wn = (wave & 1) * 32;
    const int fr = lane & 15, fq = lane >> 4;

    float4v acc[4][2] = {};

    uint4 a0 = *(const uint4*)Ap0;
    uint4 a1 = *(const uint4*)Ap1;
    uint4 b0 = *(const uint4*)Bp;

    for (int k0 = 0; k0 < K; k0 += 32) {
        __syncthreads();
        *(uint4*)&As[ar][ak]      = a0;
        *(uint4*)&As[ar + 64][ak] = a1;
        *(uint4*)&Bs[ar][ak]      = b0;
        if (k0 + 32 < K) {
            a0 = *(const uint4*)(Ap0 + k0 + 32);
            a1 = *(const uint4*)(Ap1 + k0 + 32);
            b0 = *(const uint4*)(Bp + k0 + 32);
        }
        __syncthreads();
        union { uint4 u; short8 s; } ua[4], ub[2];
        #pragma unroll
        for (int i = 0; i < 4; ++i) ua[i].u = *(const uint4*)&As[wm + i * 16 + fr][fq * 8];
        #pragma unroll
        for (int j = 0; j < 2; ++j) ub[j].u = *(const uint4*)&Bs[wn + j * 16 + fr][fq * 8];
        #pragma unroll
        for (int i = 0; i < 4; ++i)
            #pragma unroll
            for (int j = 0; j < 2; ++j)
                acc[i][j] = __builtin_amdgcn_mfma_f32_16x16x32_bf16(ua[i].s, ub[j].s, acc[i][j], 0, 0, 0);
    }

    const long long coff = (long long)zb * sCb + (long long)zh * sCh;
    #pragma unroll
    for (int i = 0; i < 4; ++i) {
        #pragma unroll
        for (int j = 0; j < 2; ++j) {
            #pragma unroll
            for (int r = 0; r < 4; ++r) {
                int m = m0 + wm + i * 16 + fq * 4 + r;
                int n = n0 + wn + j * 16 + fr;
                float v = acc[i][j][r];
                if (EPI == 1) {
                    bf16* C = (bf16*)Cv;
                    if (n < 512) {
                        C[(size_t)m * ldc + n] = __float2bfloat16(v + ldsel(bias, biasoff + n, flg));
                    } else if (n < 1024) {
                        C[(size_t)m * ldc + n] = __float2bfloat16(v);
                    } else {
                        int h = (n >> 6) & 7, d = n & 63, ii = m & 1023, bb = m >> 10;
                        aux[(size_t)(bb * 8 + h) * 65536 + (size_t)d * 1024 + ii] = __float2bfloat16(v);
                    }
                } else if (EPI == 2) {
                    float* C = (float*)Cv;
                    C[(size_t)m * ldc + n] = v + ldsel(bias, biasoff + n, flg) + resid[(size_t)m * ldc + n];
                } else if (EPI == 3) {
                    bf16* C = (bf16*)Cv;
                    float t = v + ldsel(bias, biasoff + n, flg);
                    C[(size_t)m * ldc + n] = __float2bfloat16(0.5f * t * (1.f + erff(t * 0.70710678118f)));
                } else if (EPI == 4) {
                    bf16* C = (bf16*)Cv + coff;
                    int t = m * 1025 + n + 1;
                    int ii = (t >> 10) - 1;
                    if (ii >= 0) C[(size_t)ii * 1024 + (t & 1023)] = __float2bfloat16(v * (1.f / 3.f));
                } else if (EPI == 5) {
                    bf16* C = (bf16*)Cv + coff;
                    C[(size_t)m * ldc + n] = __float2bfloat16(v);
                }
            }
        }
    }
}

// ---- fused AC + BD + softmax-over-h: block = 64x64 (i,j) tile, loops h=0..7 ----
__global__ __launch_bounds__(256) void scores_kernel(
    const bf16* __restrict__ qkvb, const bf16* __restrict__ Scb,
    bf16* __restrict__ attn, void* __restrict__ oattn, const int* __restrict__ flagp) {
    const bool bf = flagp[0] != 0;
    const int tid = threadIdx.x;
    const int lane = tid & 63, wave = tid >> 6;
    const int j0 = blockIdx.x * 64, i0 = blockIdx.y * 64, b = blockIdx.z;

    __shared__ bf16 Qs[64][72];
    __shared__ bf16 Ks[64][72];

    const int r0 = tid >> 3, c0 = (tid & 7) * 8;
    const bf16* Qp = qkvb + (size_t)(b * 1024 + i0 + r0) * 1536 + c0;
    const bf16* Kp = qkvb + (size_t)(b * 1024 + j0 + r0) * 1536 + 512 + c0;

    const int wm = (wave >> 1) * 32, wn = (wave & 1) * 32;
    const int fr = lane & 15, fq = lane >> 4;

    float4v acc[8][2][2] = {};

    for (int h = 0; h < 8; ++h) {
        __syncthreads();
        *(uint4*)&Qs[r0][c0]      = *(const uint4*)(Qp + h * 64);
        *(uint4*)&Qs[r0 + 32][c0] = *(const uint4*)(Qp + (size_t)32 * 1536 + h * 64);
        *(uint4*)&Ks[r0][c0]      = *(const uint4*)(Kp + h * 64);
        *(uint4*)&Ks[r0 + 32][c0] = *(const uint4*)(Kp + (size_t)32 * 1536 + h * 64);
        __syncthreads();
        #pragma unroll
        for (int ks = 0; ks < 2; ++ks) {
            union { uint4 u; short8 s; } ua[2], ub[2];
            #pragma unroll
            for (int i = 0; i < 2; ++i) ua[i].u = *(const uint4*)&Qs[wm + i * 16 + fr][fq * 8 + ks * 32];
            #pragma unroll
            for (int j = 0; j < 2; ++j) ub[j].u = *(const uint4*)&Ks[wn + j * 16 + fr][fq * 8 + ks * 32];
            #pragma unroll
            for (int i = 0; i < 2; ++i)
                #pragma unroll
                for (int j = 0; j < 2; ++j)
                    acc[h][i][j] = __builtin_amdgcn_mfma_f32_16x16x32_bf16(ua[i].s, ub[j].s, acc[h][i][j], 0, 0, 0);
        }
    }

    const size_t pb = (size_t)b * 8388608;
    #pragma unroll
    for (int i = 0; i < 2; ++i) {
        #pragma unroll
        for (int j = 0; j < 2; ++j) {
            #pragma unroll
            for (int r = 0; r < 4; ++r) {
                int gi = i0 + wm + i * 16 + fq * 4 + r;
                int gj = j0 + wn + j * 16 + fr;
                size_t idx = pb + (size_t)gi * 1024 + gj;
                float d[8];
                float mx = -3.4e38f;
                #pragma unroll
                for (int h = 0; h < 8; ++h) {
                    float bd = (gj == gi + 1) ? 0.f
                               : __bfloat162float(Scb[idx + (size_t)h * 1048576]);
                    float v = (acc[h][i][j][r] + bd) * 0.125f;
                    d[h] = v; mx = fmaxf(mx, v);
                }
                float s = 0.f;
                #pragma unroll
                for (int h = 0; h < 8; ++h) { d[h] = __expf(d[h] - mx); s += d[h]; }
                float inv = 1.f / s;
                #pragma unroll
                for (int h = 0; h < 8; ++h) {
                    float a = d[h] * inv;
                    attn[idx + (size_t)h * 1048576] = __float2bfloat16(a);
                    if (oattn) stsel(oattn, 1048576 + (long long)(idx + (size_t)h * 1048576), bf, a);
                }
            }
        }
    }
}

extern "C" void kernel_launch(void* const* d_in, const int* in_sizes, int n_in,
                              void* d_out, int out_size, void* d_ws, size_t ws_size,
                              hipStream_t stream) {
    (void)in_sizes; (void)n_in; (void)out_size; (void)ws_size;
    const void* x_in    = d_in[0];
    const void* r_t     = d_in[1];
    const void* r_c     = d_in[2];
    const void* r_p     = d_in[3];
    const void* bias_pf = d_in[4];
    const void* ln1_g   = d_in[5];
    const void* ln1_b   = d_in[6];
    const void* w_qkv   = d_in[7];
    const void* w_outw  = d_in[8];
    const void* b_out   = d_in[9];
    const void* w_kt    = d_in[10];
    const void* w_kc    = d_in[11];
    const void* w_kp    = d_in[12];
    const void* ln2_g   = d_in[13];
    const void* ln2_b   = d_in[14];
    const void* w_ff1   = d_in[15];
    const void* b_ff1   = d_in[16];
    const void* w_ff2   = d_in[17];
    const void* b_ff2   = d_in[18];

    float* xbuf  = (float*)d_ws;                 // 1M fp32
    bf16* base16 = (bf16*)(xbuf + 1048576);
    bf16* Scb   = base16;                        // 16M (h1 aliases first 4M)
    bf16* h1    = base16;
    bf16* attn  = base16 + 16777216;             // 16M
    bf16* xnb   = attn + 16777216;               // 1M
    bf16* qkvb  = xnb + 1048576;                 // 3M
    bf16* vT    = qkvb + 3145728;                // 1M
    bf16* wsum4 = vT + 1048576;                  // 4M (all 4 layers)
    bf16* rcat  = wsum4 + 4194304;               // 3M
    bf16* arena = rcat + 3145728;                // 15.75M (4 layers' transposed W)
    int*  flagp = (int*)(arena + 15728640);

    const int LW = 3932160;
    const int WCAT_O = 786432, OUT_O = 1572864, FF1_O = 1835008, FF2_O = 2883584;
    const int QKV_O = 0;

    dim3 blk(256);

    detect_kernel<<<1, 64, 0, stream>>>((const unsigned int*)ln1_g, flagp);
    cast_in<<<512, blk, 0, stream>>>(x_in, xbuf, 131072, flagp);
    rcat_all<<<dim3(512, 3), blk, 0, stream>>>(r_t, r_c, r_p, rcat, flagp);

    // all weight transposes in one exact-sized dispatch (3840 working blocks)
    prep_weights<<<3840, blk, 0, stream>>>(
        w_qkv, w_kt, w_kc, w_kp, w_outw, w_ff1, w_ff2, arena, flagp);

    // wsum for ALL layers in one batched dispatch (z = layer):
    // wsum4[l] = rcat @ wcatT[l]^T   (2048x512, K=1536)
    mgemm<5><<<dim3(8, 16, 4), blk, 0, stream>>>(
        rcat, 1536, 0, 0, arena + WCAT_O, 1536, 0, LW,
        wsum4, 512, 0, 1048576, 1536, nullptr, 0, nullptr, nullptr, flagp);

    for (int l = 0; l < 4; ++l) {
        const bf16* qkvT  = arena + l * LW + QKV_O;
        const bf16* outT  = arena + l * LW + OUT_O;
        const bf16* ff1T  = arena + l * LW + FF1_O;
        const bf16* ff2T  = arena + l * LW + FF2_O;
        const bf16* wsum  = wsum4 + (size_t)l * 1048576;

        // LN1 -> xnb (bf16)
        ln_kernel<<<2048, blk, 0, stream>>>(xbuf, ln1_g, l * 512, ln1_b, l * 512, xnb, flagp);
        // qkv = xnb @ qkvT^T; q += bias_pf; v -> vT
        mgemm<1><<<dim3(24, 16, 1), blk, 0, stream>>>(
            xnb, 512, 0, 0, qkvT, 512, 0, 0,
            qkvb, 1536, 0, 0, 512, bias_pf, 0, nullptr, vT, flagp);
        // Scb = rel_shift(q . wsum)/3 (scatter-store)
        mgemm<4><<<dim3(16, 8, 16), blk, 0, stream>>>(
            qkvb, 1536, 1572864, 64, wsum, 512, 524288, 64,
            Scb, 1024, 8388608, 1048576, 64, nullptr, 0, nullptr, nullptr, flagp);
        // fused AC + BD + softmax -> attn (+ d_out attn region on l=3)
        scores_kernel<<<dim3(16, 16, 2), blk, 0, stream>>>(
            qkvb, Scb, attn, (l == 3) ? d_out : nullptr, flagp);
        // out = attn @ vT^T -> xnb
        mgemm<5><<<dim3(1, 8, 16), blk, 0, stream>>>(
            attn, 1024, 8388608, 1048576, vT, 1024, 524288, 65536,
            xnb, 512, 524288, 64, 1024, nullptr, 0, nullptr, nullptr, flagp);
        // x = out @ outT^T + b_out + x (fp32)
        mgemm<2><<<dim3(8, 16, 1), blk, 0, stream>>>(
            xnb, 512, 0, 0, outT, 512, 0, 0,
            xbuf, 512, 0, 0, 512, b_out, (long long)l * 512, xbuf, nullptr, flagp);
        // LN2 -> xnb
        ln_kernel<<<2048, blk, 0, stream>>>(xbuf, ln2_g, l * 512, ln2_b, l * 512, xnb, flagp);
        // h1 = gelu(xnb @ ff1T^T + b_ff1)
        mgemm<3><<<dim3(32, 16, 1), blk, 0, stream>>>(
            xnb, 512, 0, 0, ff1T, 512, 0, 0,
            h1, 2048, 0, 0, 512, b_ff1, (long long)l * 2048, nullptr, nullptr, flagp);
        // x = h1 @ ff2T^T + b_ff2 + x (fp32)
        mgemm<2><<<dim3(8, 16, 1), blk, 0, stream>>>(
            h1, 2048, 0, 0, ff2T, 2048, 0, 0,
            xbuf, 512, 0, 0, 2048, b_ff2, (long long)l * 512, xbuf, nullptr, flagp);
    }

    cast_out<<<512, blk, 0, stream>>>(xbuf, d_out, 131072, flagp);
}

// Round 2
// 734.595 us; speedup vs baseline: 1.3589x; 1.2113x over previous
//
#include <hip/hip_runtime.h>
#include <hip/hip_bf16.h>

// B=2, N=1024, D=512, H=8, DH=64, HD=512, FF=2048, DEPTH=4.
// Dual-dtype IO (bf16 or fp32, runtime-detected from ln1_g word0).
// bf16 MFMA 16x16x32 everywhere, fp32 accum, fp32 residual chain.
// R2: Scb interleaved [ij][h] (bd_kernel packs short8, linear-in-t coalesced
//     scatter); scores 8-wave, vector bd loads, LDS-staged coalesced attn
//     writes; mgemm64 (64x64 tile) for PV/out/ff2/qkv/wsum occupancy.

using bf16 = __hip_bfloat16;
typedef __attribute__((ext_vector_type(8))) short short8;
typedef __attribute__((ext_vector_type(4))) float float4v;
typedef __attribute__((ext_vector_type(2))) unsigned int uint2v;

__device__ __forceinline__ float ldsel(const void* p, long long i, bool isbf) {
    return isbf ? __bfloat162float(((const bf16*)p)[i]) : ((const float*)p)[i];
}
__device__ __forceinline__ void stsel(void* p, long long i, bool isbf, float v) {
    if (isbf) ((bf16*)p)[i] = __float2bfloat16(v);
    else      ((float*)p)[i] = v;
}
__device__ __forceinline__ float bf2f(short u) {
    return __uint_as_float(((unsigned)(unsigned short)u) << 16);
}
__device__ __forceinline__ short f2bf(float f) {
    bf16 h = __float2bfloat16(f);
    return *reinterpret_cast<short*>(&h);
}

__global__ void detect_kernel(const unsigned int* __restrict__ g, int* __restrict__ flag) {
    if (threadIdx.x == 0) flag[0] = ((g[0] & 0xFFFFu) != 0u) ? 1 : 0;
}

__global__ __launch_bounds__(256) void cast_in(const void* __restrict__ in, float* __restrict__ out,
                                               int n8, const int* __restrict__ flagp) {
    bool bf = flagp[0] != 0;
    int i = blockIdx.x * 256 + threadIdx.x;
    if (i >= n8) return;
    long long b = (long long)i * 8;
    if (bf) {
        short8 v = *(const short8*)((const bf16*)in + b);
        float4v o0, o1;
        #pragma unroll
        for (int j = 0; j < 4; ++j) { o0[j] = bf2f(v[j]); o1[j] = bf2f(v[4 + j]); }
        *(float4v*)(out + b) = o0;
        *(float4v*)(out + b + 4) = o1;
    } else {
        float4v a0 = *(const float4v*)((const float*)in + b);
        float4v a1 = *(const float4v*)((const float*)in + b + 4);
        *(float4v*)(out + b) = a0;
        *(float4v*)(out + b + 4) = a1;
    }
}
__global__ __launch_bounds__(256) void cast_out(const float* __restrict__ in, void* __restrict__ out,
                                                int n8, const int* __restrict__ flagp) {
    bool bf = flagp[0] != 0;
    int i = blockIdx.x * 256 + threadIdx.x;
    if (i >= n8) return;
    long long b = (long long)i * 8;
    float4v a0 = *(const float4v*)(in + b);
    float4v a1 = *(const float4v*)(in + b + 4);
    if (bf) {
        short8 v;
        #pragma unroll
        for (int j = 0; j < 4; ++j) { v[j] = f2bf(a0[j]); v[4 + j] = f2bf(a1[j]); }
        *(short8*)((bf16*)out + b) = v;
    } else {
        *(float4v*)((float*)out + b) = a0;
        *(float4v*)((float*)out + b + 4) = a1;
    }
}

__global__ __launch_bounds__(256) void rcat_all(const void* __restrict__ r0, const void* __restrict__ r1,
                                                const void* __restrict__ r2, bf16* __restrict__ dst,
                                                const int* __restrict__ flagp) {
    bool bf = flagp[0] != 0;
    int s = blockIdx.y;
    const void* src = (s == 0) ? r0 : ((s == 1) ? r1 : r2);
    int i = blockIdx.x * 256 + threadIdx.x;
    int m = i >> 6, k8 = (i & 63) * 8;
    long long b = (long long)m * 512 + k8;
    short8 v;
    if (bf) {
        v = *(const short8*)((const bf16*)src + b);
    } else {
        float4v a0 = *(const float4v*)((const float*)src + b);
        float4v a1 = *(const float4v*)((const float*)src + b + 4);
        #pragma unroll
        for (int j = 0; j < 4; ++j) { v[j] = f2bf(a0[j]); v[4 + j] = f2bf(a1[j]); }
    }
    *(short8*)(dst + (size_t)m * 1536 + s * 512 + k8) = v;
}

// ---- all weight transposes (all 4 layers) in ONE exact-sized dispatch ----
__global__ __launch_bounds__(256) void prep_weights(
    const void* __restrict__ s0, const void* __restrict__ s1, const void* __restrict__ s2,
    const void* __restrict__ s3, const void* __restrict__ s4, const void* __restrict__ s5,
    const void* __restrict__ s6, bf16* __restrict__ arena,
    const int* __restrict__ flagp) {
    const bool bf = flagp[0] != 0;
    const int bid = blockIdx.x;
    const int l = bid / 960;
    const int rem = bid - l * 960;
    const int LW = 3932160;
    const int L = l * LW;

    int j, tile, tx, ldi, ldo;
    long long ioff;
    int dstoff;
    if (rem < 192)      { j = 0; tile = rem;                tx = 24; ldi = 1536; ldo = 512;
                          ioff = (long long)l * 786432;  dstoff = L; }
    else if (rem < 448) { j = 1 + ((rem - 192) >> 6); tile = (rem - 192) & 63; tx = 8; ldi = 512;
                          ioff = (long long)l * 262144;
                          if (j <= 3) { ldo = 1536; dstoff = L + 786432 + (j - 1) * 512; }
                          else        { ldo = 512;  dstoff = L + 1572864; } }
    else if (rem < 704) { j = 5; tile = rem - 448;          tx = 32; ldi = 2048; ldo = 512;
                          ioff = (long long)l * 1048576; dstoff = L + 1835008; }
    else                { j = 6; tile = rem - 704;          tx = 8;  ldi = 512;  ldo = 2048;
                          ioff = (long long)l * 1048576; dstoff = L + 2883584; }
    const void* in = (j == 0) ? s0 : (j == 1) ? s1 : (j == 2) ? s2 :
                     (j == 3) ? s3 : (j == 4) ? s4 : (j == 5) ? s5 : s6;
    bf16* out = arena + dstoff;
    const int bx = tile % tx, by = tile / tx;
    const int n0 = bx * 64, k0 = by * 64;
    const int tid = threadIdx.x;

    __shared__ bf16 t[64][72];

    if (bf) {
        const bf16* inb = (const bf16*)in + ioff;
        #pragma unroll
        for (int p = 0; p < 2; ++p) {
            int e = tid + p * 256;
            int r = e >> 3, c = (e & 7) * 8;
            *(uint4*)&t[r][c] = *(const uint4*)(inb + (size_t)(k0 + r) * ldi + n0 + c);
        }
    } else {
        const float* inf = (const float*)in + ioff;
        #pragma unroll
        for (int p = 0; p < 4; ++p) {
            int e = tid + p * 256;
            int r = e >> 4, c = (e & 15) * 4;
            float4v v = *(const float4v*)(inf + (size_t)(k0 + r) * ldi + n0 + c);
            union { bf16 h[4]; uint2v u; } w;
            #pragma unroll
            for (int q = 0; q < 4; ++q) w.h[q] = __float2bfloat16(v[q]);
            *reinterpret_cast<uint2v*>(&t[r][c]) = w.u;
        }
    }
    __syncthreads();
    #pragma unroll
    for (int p = 0; p < 2; ++p) {
        int e = tid + p * 256;
        int r = e >> 3, c = (e & 7) * 8;
        union { short8 s; uint4 u; } o;
        #pragma unroll
        for (int q = 0; q < 8; ++q)
            o.s[q] = *reinterpret_cast<const short*>(&t[c + q][r]);
        *(uint4*)(out + (size_t)(n0 + r) * ldo + k0 + c) = o.u;
    }
}

// ---- layernorm ----
__global__ __launch_bounds__(256) void ln_kernel(const float* __restrict__ x,
                                                 const void* __restrict__ g, long long goff,
                                                 const void* __restrict__ bta, long long boff,
                                                 bf16* __restrict__ out,
                                                 const int* __restrict__ flagp) {
    bool bf = flagp[0] != 0;
    int row = blockIdx.x;
    const float* xr = x + (size_t)row * 512;
    int tid = threadIdx.x;
    float v0 = xr[tid], v1 = xr[tid + 256];
    float s = v0 + v1, q = v0 * v0 + v1 * v1;
    #pragma unroll
    for (int off = 32; off; off >>= 1) {
        s += __shfl_down(s, off);
        q += __shfl_down(q, off);
    }
    __shared__ float ls[4], lq[4];
    int wid = tid >> 6, lane = tid & 63;
    if (lane == 0) { ls[wid] = s; lq[wid] = q; }
    __syncthreads();
    if (tid == 0) {
        float ts = ls[0] + ls[1] + ls[2] + ls[3];
        float tq = lq[0] + lq[1] + lq[2] + lq[3];
        float m = ts * (1.f / 512.f);
        float var = tq * (1.f / 512.f) - m * m;
        ls[0] = m; lq[0] = rsqrtf(var + 1e-5f);
    }
    __syncthreads();
    float m = ls[0], r = lq[0];
    out[(size_t)row * 512 + tid] =
        __float2bfloat16((v0 - m) * r * ldsel(g, goff + tid, bf) + ldsel(bta, boff + tid, bf));
    out[(size_t)row * 512 + tid + 256] =
        __float2bfloat16((v1 - m) * r * ldsel(g, goff + tid + 256, bf) + ldsel(bta, boff + tid + 256, bf));
}

// ---- MFMA GEMM 128x64 tile (4 waves, 64x32 per wave). EPI as before. ----
template<int EPI>
__global__ __launch_bounds__(256) void mgemm(
    const bf16* __restrict__ A, int lda, long long sAb, long long sAh,
    const bf16* __restrict__ B, int ldb, long long sBb, long long sBh,
    void* __restrict__ Cv, int ldc, long long sCb, long long sCh,
    int K,
    const void* __restrict__ bias, long long biasoff,
    float* __restrict__ resid,
    bf16* __restrict__ aux,
    const int* __restrict__ flagp) {
    const bool flg = flagp[0] != 0;
    const int tid = threadIdx.x;
    const int lane = tid & 63, wave = tid >> 6;
    const int m0 = blockIdx.y * 128, n0 = blockIdx.x * 64;
    const int zb = (int)(blockIdx.z >> 3), zh = (int)(blockIdx.z & 7);
    A += (size_t)zb * sAb + (size_t)zh * sAh;
    B += (size_t)zb * sBb + (size_t)zh * sBh;

    __shared__ bf16 As[128][40];
    __shared__ bf16 Bs[64][40];

    const int ar = tid >> 2, ak = (tid & 3) * 8;
    const bf16* Ap0 = A + (size_t)(m0 + ar) * lda + ak;
    const bf16* Ap1 = Ap0 + (size_t)64 * lda;
    const bf16* Bp  = B + (size_t)(n0 + ar) * ldb + ak;

    const int wm = (wave >> 1) * 64, wn = (wave & 1) * 32;
    const int fr = lane & 15, fq = lane >> 4;

    float4v acc[4][2] = {};

    uint4 a0 = *(const uint4*)Ap0;
    uint4 a1 = *(const uint4*)Ap1;
    uint4 b0 = *(const uint4*)Bp;

    for (int k0 = 0; k0 < K; k0 += 32) {
        __syncthreads();
        *(uint4*)&As[ar][ak]      = a0;
        *(uint4*)&As[ar + 64][ak] = a1;
        *(uint4*)&Bs[ar][ak]      = b0;
        if (k0 + 32 < K) {
            a0 = *(const uint4*)(Ap0 + k0 + 32);
            a1 = *(const uint4*)(Ap1 + k0 + 32);
            b0 = *(const uint4*)(Bp + k0 + 32);
        }
        __syncthreads();
        union { uint4 u; short8 s; } ua[4], ub[2];
        #pragma unroll
        for (int i = 0; i < 4; ++i) ua[i].u = *(const uint4*)&As[wm + i * 16 + fr][fq * 8];
        #pragma unroll
        for (int j = 0; j < 2; ++j) ub[j].u = *(const uint4*)&Bs[wn + j * 16 + fr][fq * 8];
        #pragma unroll
        for (int i = 0; i < 4; ++i)
            #pragma unroll
            for (int j = 0; j < 2; ++j)
                acc[i][j] = __builtin_amdgcn_mfma_f32_16x16x32_bf16(ua[i].s, ub[j].s, acc[i][j], 0, 0, 0);
    }

    const long long coff = (long long)zb * sCb + (long long)zh * sCh;
    #pragma unroll
    for (int i = 0; i < 4; ++i) {
        #pragma unroll
        for (int j = 0; j < 2; ++j) {
            #pragma unroll
            for (int r = 0; r < 4; ++r) {
                int m = m0 + wm + i * 16 + fq * 4 + r;
                int n = n0 + wn + j * 16 + fr;
                float v = acc[i][j][r];
                if (EPI == 1) {
                    bf16* C = (bf16*)Cv;
                    if (n < 512) {
                        C[(size_t)m * ldc + n] = __float2bfloat16(v + ldsel(bias, biasoff + n, flg));
                    } else if (n < 1024) {
                        C[(size_t)m * ldc + n] = __float2bfloat16(v);
                    } else {
                        int h = (n >> 6) & 7, d = n & 63, ii = m & 1023, bb = m >> 10;
                        aux[(size_t)(bb * 8 + h) * 65536 + (size_t)d * 1024 + ii] = __float2bfloat16(v);
                    }
                } else if (EPI == 2) {
                    float* C = (float*)Cv;
                    C[(size_t)m * ldc + n] = v + ldsel(bias, biasoff + n, flg) + resid[(size_t)m * ldc + n];
                } else if (EPI == 3) {
                    bf16* C = (bf16*)Cv;
                    float t = v + ldsel(bias, biasoff + n, flg);
                    C[(size_t)m * ldc + n] = __float2bfloat16(0.5f * t * (1.f + erff(t * 0.70710678118f)));
                } else if (EPI == 5) {
                    bf16* C = (bf16*)Cv + coff;
                    C[(size_t)m * ldc + n] = __float2bfloat16(v);
                }
            }
        }
    }
}

// ---- MFMA GEMM 64x64 tile (4 waves, 32x32 per wave) — occupancy variant ----
template<int EPI>
__global__ __launch_bounds__(256) void mgemm64(
    const bf16* __restrict__ A, int lda, long long sAb, long long sAh,
    const bf16* __restrict__ B, int ldb, long long sBb, long long sBh,
    void* __restrict__ Cv, int ldc, long long sCb, long long sCh,
    int K,
    const void* __restrict__ bias, long long biasoff,
    float* __restrict__ resid,
    bf16* __restrict__ aux,
    const int* __restrict__ flagp) {
    const bool flg = flagp[0] != 0;
    const int tid = threadIdx.x;
    const int lane = tid & 63, wave = tid >> 6;
    const int m0 = blockIdx.y * 64, n0 = blockIdx.x * 64;
    const int zb = (int)(blockIdx.z >> 3), zh = (int)(blockIdx.z & 7);
    A += (size_t)zb * sAb + (size_t)zh * sAh;
    B += (size_t)zb * sBb + (size_t)zh * sBh;

    __shared__ bf16 As[64][40];
    __shared__ bf16 Bs[64][40];

    const int ar = tid >> 2, ak = (tid & 3) * 8;
    const bf16* Ap = A + (size_t)(m0 + ar) * lda + ak;
    const bf16* Bp = B + (size_t)(n0 + ar) * ldb + ak;

    const int wm = (wave >> 1) * 32, wn = (wave & 1) * 32;
    const int fr = lane & 15, fq = lane >> 4;

    float4v acc[2][2] = {};

    uint4 a0 = *(const uint4*)Ap;
    uint4 b0 = *(const uint4*)Bp;

    for (int k0 = 0; k0 < K; k0 += 32) {
        __syncthreads();
        *(uint4*)&As[ar][ak] = a0;
        *(uint4*)&Bs[ar][ak] = b0;
        if (k0 + 32 < K) {
            a0 = *(const uint4*)(Ap + k0 + 32);
            b0 = *(const uint4*)(Bp + k0 + 32);
        }
        __syncthreads();
        union { uint4 u; short8 s; } ua[2], ub[2];
        #pragma unroll
        for (int i = 0; i < 2; ++i) ua[i].u = *(const uint4*)&As[wm + i * 16 + fr][fq * 8];
        #pragma unroll
        for (int j = 0; j < 2; ++j) ub[j].u = *(const uint4*)&Bs[wn + j * 16 + fr][fq * 8];
        #pragma unroll
        for (int i = 0; i < 2; ++i)
            #pragma unroll
            for (int j = 0; j < 2; ++j)
                acc[i][j] = __builtin_amdgcn_mfma_f32_16x16x32_bf16(ua[i].s, ub[j].s, acc[i][j], 0, 0, 0);
    }

    const long long coff = (long long)zb * sCb + (long long)zh * sCh;
    #pragma unroll
    for (int i = 0; i < 2; ++i) {
        #pragma unroll
        for (int j = 0; j < 2; ++j) {
            #pragma unroll
            for (int r = 0; r < 4; ++r) {
                int m = m0 + wm + i * 16 + fq * 4 + r;
                int n = n0 + wn + j * 16 + fr;
                float v = acc[i][j][r];
                if (EPI == 1) {
                    bf16* C = (bf16*)Cv;
                    if (n < 512) {
                        C[(size_t)m * ldc + n] = __float2bfloat16(v + ldsel(bias, biasoff + n, flg));
                    } else if (n < 1024) {
                        C[(size_t)m * ldc + n] = __float2bfloat16(v);
                    } else {
                        int h = (n >> 6) & 7, d = n & 63, ii = m & 1023, bb = m >> 10;
                        aux[(size_t)(bb * 8 + h) * 65536 + (size_t)d * 1024 + ii] = __float2bfloat16(v);
                    }
                } else if (EPI == 2) {
                    float* C = (float*)Cv;
                    C[(size_t)m * ldc + n] = v + ldsel(bias, biasoff + n, flg) + resid[(size_t)m * ldc + n];
                } else if (EPI == 5) {
                    bf16* C = (bf16*)Cv + coff;
                    C[(size_t)m * ldc + n] = __float2bfloat16(v);
                }
            }
        }
    }
}

// ---- BD producer: P = (q . wsum)/3 for all 8 heads, rel-shift scatter into
// interleaved Scb[(t-1024)*8 + h]. Address is LINEAR in t -> coalesced 16B/lane.
__global__ __launch_bounds__(512) void bd_kernel(
    const bf16* __restrict__ qkvb, const bf16* __restrict__ wsum,
    bf16* __restrict__ Scb) {
    const int tid = threadIdx.x;
    const int lane = tid & 63, wave = tid >> 6;
    const int n0 = blockIdx.x * 64, m0 = blockIdx.y * 64, b = blockIdx.z;

    __shared__ bf16 Qs[64][72];
    __shared__ bf16 Ws[64][72];

    const int r0 = tid >> 3, c0 = (tid & 7) * 8;
    const bf16* Qp = qkvb + (size_t)(b * 1024 + m0 + r0) * 1536 + c0;
    const bf16* Wp = wsum + (size_t)(b * 1024 + n0 + r0) * 512 + c0;

    const int wm = (wave >> 2) * 32, wn = (wave & 3) * 16;
    const int fr = lane & 15, fq = lane >> 4;

    float4v acc[8][2] = {};

    for (int h = 0; h < 8; ++h) {
        __syncthreads();
        *(uint4*)&Qs[r0][c0] = *(const uint4*)(Qp + h * 64);
        *(uint4*)&Ws[r0][c0] = *(const uint4*)(Wp + h * 64);
        __syncthreads();
        #pragma unroll
        for (int ks = 0; ks < 2; ++ks) {
            union { uint4 u; short8 s; } ua[2], ub;
            #pragma unroll
            for (int i = 0; i < 2; ++i) ua[i].u = *(const uint4*)&Qs[wm + i * 16 + fr][fq * 8 + ks * 32];
            ub.u = *(const uint4*)&Ws[wn + fr][fq * 8 + ks * 32];
            #pragma unroll
            for (int i = 0; i < 2; ++i)
                acc[h][i] = __builtin_amdgcn_mfma_f32_16x16x32_bf16(ua[i].s, ub.s, acc[h][i], 0, 0, 0);
        }
    }

    const size_t pb = (size_t)b * 8388608;
    #pragma unroll
    for (int i = 0; i < 2; ++i) {
        #pragma unroll
        for (int r = 0; r < 4; ++r) {
            int m = m0 + wm + i * 16 + fq * 4 + r;
            int n = n0 + wn + fr;
            int t = m * 1025 + n + 1;
            if (t >= 1024) {
                short8 v;
                #pragma unroll
                for (int h = 0; h < 8; ++h) v[h] = f2bf(acc[h][i][r] * (1.f / 3.f));
                *(short8*)(Scb + pb + (size_t)(t - 1024) * 8) = v;
            }
        }
    }
}

// ---- fused AC + BD + softmax-over-h. 8 waves, 64x64 (i,j) tile. ----
// Scb interleaved (one 16B load per element); attn written via LDS staging
// (full 128B rows). oattn (l=3) written scattered from fp32 registers.
__global__ __launch_bounds__(512) void scores_kernel(
    const bf16* __restrict__ qkvb, const bf16* __restrict__ Scb,
    bf16* __restrict__ attn, void* __restrict__ oattn, const int* __restrict__ flagp) {
    const bool bf = flagp[0] != 0;
    const int tid = threadIdx.x;
    const int lane = tid & 63, wave = tid >> 6;
    const int j0 = blockIdx.x * 64, i0 = blockIdx.y * 64, b = blockIdx.z;

    __shared__ bf16 Qs[64][72];
    __shared__ bf16 Ks[64][72];

    const int r0 = tid >> 3, c0 = (tid & 7) * 8;
    const bf16* Qp = qkvb + (size_t)(b * 1024 + i0 + r0) * 1536 + c0;
    const bf16* Kp = qkvb + (size_t)(b * 1024 + j0 + r0) * 1536 + 512 + c0;

    const int wm = (wave >> 2) * 32, wn = (wave & 3) * 16;
    const int fr = lane & 15, fq = lane >> 4;

    float4v acc[8][2] = {};

    for (int h = 0; h < 8; ++h) {
        __syncthreads();
        *(uint4*)&Qs[r0][c0] = *(const uint4*)(Qp + h * 64);
        *(uint4*)&Ks[r0][c0] = *(const uint4*)(Kp + h * 64);
        __syncthreads();
        #pragma unroll
        for (int ks = 0; ks < 2; ++ks) {
            union { uint4 u; short8 s; } ua[2], ub;
            #pragma unroll
            for (int i = 0; i < 2; ++i) ua[i].u = *(const uint4*)&Qs[wm + i * 16 + fr][fq * 8 + ks * 32];
            ub.u = *(const uint4*)&Ks[wn + fr][fq * 8 + ks * 32];
            #pragma unroll
            for (int i = 0; i < 2; ++i)
                acc[h][i] = __builtin_amdgcn_mfma_f32_16x16x32_bf16(ua[i].s, ub.s, acc[h][i], 0, 0, 0);
        }
    }

    // pass 1: per-element max + inv-sum over h (bd kept in registers)
    short8 bdv[8];
    float mxs[8], invs[8];
    const size_t pb = (size_t)b * 8388608;
    #pragma unroll
    for (int i = 0; i < 2; ++i) {
        #pragma unroll
        for (int r = 0; r < 4; ++r) {
            const int e = i * 4 + r;
            int gi = i0 + wm + i * 16 + fq * 4 + r;
            int gj = j0 + wn + fr;
            bdv[e] = *(const short8*)(Scb + pb + ((size_t)gi * 1024 + gj) * 8);
            bool diag = (gj == gi + 1);
            float dv[8];
            float mx = -3.4e38f;
            #pragma unroll
            for (int h = 0; h < 8; ++h) {
                float bd = diag ? 0.f : bf2f(bdv[e][h]);
                dv[h] = (acc[h][i][r] + bd) * 0.125f;
                mx = fmaxf(mx, dv[h]);
            }
            float s = 0.f;
            #pragma unroll
            for (int h = 0; h < 8; ++h) s += __expf(dv[h] - mx);
            mxs[e] = mx; invs[e] = 1.f / s;
        }
    }

    // pass 2: per h, stage 64x64 bf16 tile in LDS (Qs reused), write full rows.
    const size_t ab = (size_t)b * 8388608;
    const int orow = tid >> 3, ocol = (tid & 7) * 8;
    #pragma unroll
    for (int h = 0; h < 8; ++h) {
        __syncthreads();
        #pragma unroll
        for (int i = 0; i < 2; ++i) {
            #pragma unroll
            for (int r = 0; r < 4; ++r) {
                const int e = i * 4 + r;
                int gil = wm + i * 16 + fq * 4 + r;
                int gjl = wn + fr;
                int gi = i0 + gil, gj = j0 + gjl;
                float bd = (gj == gi + 1) ? 0.f : bf2f(bdv[e][h]);
                float a = __expf((acc[h][i][r] + bd) * 0.125f - mxs[e]) * invs[e];
                Qs[gil][gjl] = __float2bfloat16(a);
                if (oattn)
                    stsel(oattn, 1048576 + (long long)(ab + (size_t)h * 1048576
                          + (size_t)gi * 1024 + gj), bf, a);
            }
        }
        __syncthreads();
        *(uint4*)(attn + ab + (size_t)h * 1048576 + (size_t)(i0 + orow) * 1024 + j0 + ocol)
            = *(const uint4*)&Qs[orow][ocol];
    }
}

extern "C" void kernel_launch(void* const* d_in, const int* in_sizes, int n_in,
                              void* d_out, int out_size, void* d_ws, size_t ws_size,
                              hipStream_t stream) {
    (void)in_sizes; (void)n_in; (void)out_size; (void)ws_size;
    const void* x_in    = d_in[0];
    const void* r_t     = d_in[1];
    const void* r_c     = d_in[2];
    const void* r_p     = d_in[3];
    const void* bias_pf = d_in[4];
    const void* ln1_g   = d_in[5];
    const void* ln1_b   = d_in[6];
    const void* w_qkv   = d_in[7];
    const void* w_outw  = d_in[8];
    const void* b_out   = d_in[9];
    const void* w_kt    = d_in[10];
    const void* w_kc    = d_in[11];
    const void* w_kp    = d_in[12];
    const void* ln2_g   = d_in[13];
    const void* ln2_b   = d_in[14];
    const void* w_ff1   = d_in[15];
    const void* b_ff1   = d_in[16];
    const void* w_ff2   = d_in[17];
    const void* b_ff2   = d_in[18];

    float* xbuf  = (float*)d_ws;                 // 1M fp32
    bf16* base16 = (bf16*)(xbuf + 1048576);
    bf16* Scb   = base16;                        // 16M (h1 aliases first 4M)
    bf16* h1    = base16;
    bf16* attn  = base16 + 16777216;             // 16M
    bf16* xnb   = attn + 16777216;               // 1M
    bf16* qkvb  = xnb + 1048576;                 // 3M
    bf16* vT    = qkvb + 3145728;                // 1M
    bf16* wsum4 = vT + 1048576;                  // 4M (all 4 layers)
    bf16* rcat  = wsum4 + 4194304;               // 3M
    bf16* arena = rcat + 3145728;                // 15.75M
    int*  flagp = (int*)(arena + 15728640);

    const int LW = 3932160;
    const int WCAT_O = 786432, OUT_O = 1572864, FF1_O = 1835008, FF2_O = 2883584;
    const int QKV_O = 0;

    dim3 blk(256), blk8(512);

    detect_kernel<<<1, 64, 0, stream>>>((const unsigned int*)ln1_g, flagp);
    cast_in<<<512, blk, 0, stream>>>(x_in, xbuf, 131072, flagp);
    rcat_all<<<dim3(512, 3), blk, 0, stream>>>(r_t, r_c, r_p, rcat, flagp);

    prep_weights<<<3840, blk, 0, stream>>>(
        w_qkv, w_kt, w_kc, w_kp, w_outw, w_ff1, w_ff2, arena, flagp);

    // wsum for ALL layers, batched (z = layer): wsum4[l] = rcat @ wcatT[l]^T
    mgemm64<5><<<dim3(8, 32, 4), blk, 0, stream>>>(
        rcat, 1536, 0, 0, arena + WCAT_O, 1536, 0, LW,
        wsum4, 512, 0, 1048576, 1536, nullptr, 0, nullptr, nullptr, flagp);

    for (int l = 0; l < 4; ++l) {
        const bf16* qkvT  = arena + l * LW + QKV_O;
        const bf16* outT  = arena + l * LW + OUT_O;
        const bf16* ff1T  = arena + l * LW + FF1_O;
        const bf16* ff2T  = arena + l * LW + FF2_O;
        const bf16* wsum  = wsum4 + (size_t)l * 1048576;

        // LN1 -> xnb (bf16)
        ln_kernel<<<2048, blk, 0, stream>>>(xbuf, ln1_g, l * 512, ln1_b, l * 512, xnb, flagp);
        // qkv = xnb @ qkvT^T; q += bias_pf; v -> vT
        mgemm64<1><<<dim3(24, 32, 1), blk, 0, stream>>>(
            xnb, 512, 0, 0, qkvT, 512, 0, 0,
            qkvb, 1536, 0, 0, 512, bias_pf, 0, nullptr, vT, flagp);
        // Scb[(t-1024)*8+h] = rel_shift(q . wsum)/3, packed over h
        bd_kernel<<<dim3(16, 16, 2), blk8, 0, stream>>>(qkvb, wsum, Scb);
        // fused AC + BD + softmax -> attn (+ d_out attn region on l=3)
        scores_kernel<<<dim3(16, 16, 2), blk8, 0, stream>>>(
            qkvb, Scb, attn, (l == 3) ? d_out : nullptr, flagp);
        // out = attn @ vT^T -> xnb
        mgemm64<5><<<dim3(1, 16, 16), blk, 0, stream>>>(
            attn, 1024, 8388608, 1048576, vT, 1024, 524288, 65536,
            xnb, 512, 524288, 64, 1024, nullptr, 0, nullptr, nullptr, flagp);
        // x = out @ outT^T + b_out + x (fp32)
        mgemm64<2><<<dim3(8, 32, 1), blk, 0, stream>>>(
            xnb, 512, 0, 0, outT, 512, 0, 0,
            xbuf, 512, 0, 0, 512, b_out, (long long)l * 512, xbuf, nullptr, flagp);
        // LN2 -> xnb
        ln_kernel<<<2048, blk, 0, stream>>>(xbuf, ln2_g, l * 512, ln2_b, l * 512, xnb, flagp);
        // h1 = gelu(xnb @ ff1T^T + b_ff1)
        mgemm<3><<<dim3(32, 16, 1), blk, 0, stream>>>(
            xnb, 512, 0, 0, ff1T, 512, 0, 0,
            h1, 2048, 0, 0, 512, b_ff1, (long long)l * 2048, nullptr, nullptr, flagp);
        // x = h1 @ ff2T^T + b_ff2 + x (fp32)
        mgemm64<2><<<dim3(8, 32, 1), blk, 0, stream>>>(
            h1, 2048, 0, 0, ff2T, 2048, 0, 0,
            xbuf, 512, 0, 0, 2048, b_ff2, (long long)l * 512, xbuf, nullptr, flagp);
    }

    cast_out<<<512, blk, 0, stream>>>(xbuf, d_out, 131072, flagp);
}

// Round 3
// 715.052 us; speedup vs baseline: 1.3960x; 1.0273x over previous
//
#include <hip/hip_runtime.h>
#include <hip/hip_bf16.h>

// B=2, N=1024, D=512, H=8, DH=64, HD=512, FF=2048, DEPTH=4.
// Dual-dtype IO (bf16 or fp32, runtime-detected from ln1_g word0).
// bf16 MFMA 16x16x32 everywhere, fp32 accum, fp32 residual chain.
// R3: register-prefetch (async-STAGE split) in scores/bd h-loops; oattn
//     scatter removed from scores -> dedicated coalesced attn_out kernel.

using bf16 = __hip_bfloat16;
typedef __attribute__((ext_vector_type(8))) short short8;
typedef __attribute__((ext_vector_type(4))) float float4v;
typedef __attribute__((ext_vector_type(2))) unsigned int uint2v;

__device__ __forceinline__ float ldsel(const void* p, long long i, bool isbf) {
    return isbf ? __bfloat162float(((const bf16*)p)[i]) : ((const float*)p)[i];
}
__device__ __forceinline__ void stsel(void* p, long long i, bool isbf, float v) {
    if (isbf) ((bf16*)p)[i] = __float2bfloat16(v);
    else      ((float*)p)[i] = v;
}
__device__ __forceinline__ float bf2f(short u) {
    return __uint_as_float(((unsigned)(unsigned short)u) << 16);
}
__device__ __forceinline__ short f2bf(float f) {
    bf16 h = __float2bfloat16(f);
    return *reinterpret_cast<short*>(&h);
}

__global__ void detect_kernel(const unsigned int* __restrict__ g, int* __restrict__ flag) {
    if (threadIdx.x == 0) flag[0] = ((g[0] & 0xFFFFu) != 0u) ? 1 : 0;
}

__global__ __launch_bounds__(256) void cast_in(const void* __restrict__ in, float* __restrict__ out,
                                               int n8, const int* __restrict__ flagp) {
    bool bf = flagp[0] != 0;
    int i = blockIdx.x * 256 + threadIdx.x;
    if (i >= n8) return;
    long long b = (long long)i * 8;
    if (bf) {
        short8 v = *(const short8*)((const bf16*)in + b);
        float4v o0, o1;
        #pragma unroll
        for (int j = 0; j < 4; ++j) { o0[j] = bf2f(v[j]); o1[j] = bf2f(v[4 + j]); }
        *(float4v*)(out + b) = o0;
        *(float4v*)(out + b + 4) = o1;
    } else {
        float4v a0 = *(const float4v*)((const float*)in + b);
        float4v a1 = *(const float4v*)((const float*)in + b + 4);
        *(float4v*)(out + b) = a0;
        *(float4v*)(out + b + 4) = a1;
    }
}
__global__ __launch_bounds__(256) void cast_out(const float* __restrict__ in, void* __restrict__ out,
                                                int n8, const int* __restrict__ flagp) {
    bool bf = flagp[0] != 0;
    int i = blockIdx.x * 256 + threadIdx.x;
    if (i >= n8) return;
    long long b = (long long)i * 8;
    float4v a0 = *(const float4v*)(in + b);
    float4v a1 = *(const float4v*)(in + b + 4);
    if (bf) {
        short8 v;
        #pragma unroll
        for (int j = 0; j < 4; ++j) { v[j] = f2bf(a0[j]); v[4 + j] = f2bf(a1[j]); }
        *(short8*)((bf16*)out + b) = v;
    } else {
        *(float4v*)((float*)out + b) = a0;
        *(float4v*)((float*)out + b + 4) = a1;
    }
}

// attn (bf16, layout b*8M + h*1M + i*1024 + j) -> d_out attn region (coalesced)
__global__ __launch_bounds__(256) void attn_out(const bf16* __restrict__ attn,
                                                void* __restrict__ out,
                                                const int* __restrict__ flagp) {
    bool bf = flagp[0] != 0;
    long long e = ((long long)blockIdx.x * 256 + threadIdx.x) * 8;   // < 16777216
    short8 v = *(const short8*)(attn + e);
    if (bf) {
        *(short8*)((bf16*)out + 1048576 + e) = v;
    } else {
        float4v o0, o1;
        #pragma unroll
        for (int j = 0; j < 4; ++j) { o0[j] = bf2f(v[j]); o1[j] = bf2f(v[4 + j]); }
        float* op = (float*)out + 1048576 + e;
        *(float4v*)op = o0;
        *(float4v*)(op + 4) = o1;
    }
}

__global__ __launch_bounds__(256) void rcat_all(const void* __restrict__ r0, const void* __restrict__ r1,
                                                const void* __restrict__ r2, bf16* __restrict__ dst,
                                                const int* __restrict__ flagp) {
    bool bf = flagp[0] != 0;
    int s = blockIdx.y;
    const void* src = (s == 0) ? r0 : ((s == 1) ? r1 : r2);
    int i = blockIdx.x * 256 + threadIdx.x;
    int m = i >> 6, k8 = (i & 63) * 8;
    long long b = (long long)m * 512 + k8;
    short8 v;
    if (bf) {
        v = *(const short8*)((const bf16*)src + b);
    } else {
        float4v a0 = *(const float4v*)((const float*)src + b);
        float4v a1 = *(const float4v*)((const float*)src + b + 4);
        #pragma unroll
        for (int j = 0; j < 4; ++j) { v[j] = f2bf(a0[j]); v[4 + j] = f2bf(a1[j]); }
    }
    *(short8*)(dst + (size_t)m * 1536 + s * 512 + k8) = v;
}

// ---- all weight transposes (all 4 layers) in ONE exact-sized dispatch ----
__global__ __launch_bounds__(256) void prep_weights(
    const void* __restrict__ s0, const void* __restrict__ s1, const void* __restrict__ s2,
    const void* __restrict__ s3, const void* __restrict__ s4, const void* __restrict__ s5,
    const void* __restrict__ s6, bf16* __restrict__ arena,
    const int* __restrict__ flagp) {
    const bool bf = flagp[0] != 0;
    const int bid = blockIdx.x;
    const int l = bid / 960;
    const int rem = bid - l * 960;
    const int LW = 3932160;
    const int L = l * LW;

    int j, tile, tx, ldi, ldo;
    long long ioff;
    int dstoff;
    if (rem < 192)      { j = 0; tile = rem;                tx = 24; ldi = 1536; ldo = 512;
                          ioff = (long long)l * 786432;  dstoff = L; }
    else if (rem < 448) { j = 1 + ((rem - 192) >> 6); tile = (rem - 192) & 63; tx = 8; ldi = 512;
                          ioff = (long long)l * 262144;
                          if (j <= 3) { ldo = 1536; dstoff = L + 786432 + (j - 1) * 512; }
                          else        { ldo = 512;  dstoff = L + 1572864; } }
    else if (rem < 704) { j = 5; tile = rem - 448;          tx = 32; ldi = 2048; ldo = 512;
                          ioff = (long long)l * 1048576; dstoff = L + 1835008; }
    else                { j = 6; tile = rem - 704;          tx = 8;  ldi = 512;  ldo = 2048;
                          ioff = (long long)l * 1048576; dstoff = L + 2883584; }
    const void* in = (j == 0) ? s0 : (j == 1) ? s1 : (j == 2) ? s2 :
                     (j == 3) ? s3 : (j == 4) ? s4 : (j == 5) ? s5 : s6;
    bf16* out = arena + dstoff;
    const int bx = tile % tx, by = tile / tx;
    const int n0 = bx * 64, k0 = by * 64;
    const int tid = threadIdx.x;

    __shared__ bf16 t[64][72];

    if (bf) {
        const bf16* inb = (const bf16*)in + ioff;
        #pragma unroll
        for (int p = 0; p < 2; ++p) {
            int e = tid + p * 256;
            int r = e >> 3, c = (e & 7) * 8;
            *(uint4*)&t[r][c] = *(const uint4*)(inb + (size_t)(k0 + r) * ldi + n0 + c);
        }
    } else {
        const float* inf = (const float*)in + ioff;
        #pragma unroll
        for (int p = 0; p < 4; ++p) {
            int e = tid + p * 256;
            int r = e >> 4, c = (e & 15) * 4;
            float4v v = *(const float4v*)(inf + (size_t)(k0 + r) * ldi + n0 + c);
            union { bf16 h[4]; uint2v u; } w;
            #pragma unroll
            for (int q = 0; q < 4; ++q) w.h[q] = __float2bfloat16(v[q]);
            *reinterpret_cast<uint2v*>(&t[r][c]) = w.u;
        }
    }
    __syncthreads();
    #pragma unroll
    for (int p = 0; p < 2; ++p) {
        int e = tid + p * 256;
        int r = e >> 3, c = (e & 7) * 8;
        union { short8 s; uint4 u; } o;
        #pragma unroll
        for (int q = 0; q < 8; ++q)
            o.s[q] = *reinterpret_cast<const short*>(&t[c + q][r]);
        *(uint4*)(out + (size_t)(n0 + r) * ldo + k0 + c) = o.u;
    }
}

// ---- layernorm ----
__global__ __launch_bounds__(256) void ln_kernel(const float* __restrict__ x,
                                                 const void* __restrict__ g, long long goff,
                                                 const void* __restrict__ bta, long long boff,
                                                 bf16* __restrict__ out,
                                                 const int* __restrict__ flagp) {
    bool bf = flagp[0] != 0;
    int row = blockIdx.x;
    const float* xr = x + (size_t)row * 512;
    int tid = threadIdx.x;
    float v0 = xr[tid], v1 = xr[tid + 256];
    float s = v0 + v1, q = v0 * v0 + v1 * v1;
    #pragma unroll
    for (int off = 32; off; off >>= 1) {
        s += __shfl_down(s, off);
        q += __shfl_down(q, off);
    }
    __shared__ float ls[4], lq[4];
    int wid = tid >> 6, lane = tid & 63;
    if (lane == 0) { ls[wid] = s; lq[wid] = q; }
    __syncthreads();
    if (tid == 0) {
        float ts = ls[0] + ls[1] + ls[2] + ls[3];
        float tq = lq[0] + lq[1] + lq[2] + lq[3];
        float m = ts * (1.f / 512.f);
        float var = tq * (1.f / 512.f) - m * m;
        ls[0] = m; lq[0] = rsqrtf(var + 1e-5f);
    }
    __syncthreads();
    float m = ls[0], r = lq[0];
    out[(size_t)row * 512 + tid] =
        __float2bfloat16((v0 - m) * r * ldsel(g, goff + tid, bf) + ldsel(bta, boff + tid, bf));
    out[(size_t)row * 512 + tid + 256] =
        __float2bfloat16((v1 - m) * r * ldsel(g, goff + tid + 256, bf) + ldsel(bta, boff + tid + 256, bf));
}

// ---- MFMA GEMM 128x64 tile (4 waves, 64x32 per wave). ----
template<int EPI>
__global__ __launch_bounds__(256) void mgemm(
    const bf16* __restrict__ A, int lda, long long sAb, long long sAh,
    const bf16* __restrict__ B, int ldb, long long sBb, long long sBh,
    void* __restrict__ Cv, int ldc, long long sCb, long long sCh,
    int K,
    const void* __restrict__ bias, long long biasoff,
    float* __restrict__ resid,
    bf16* __restrict__ aux,
    const int* __restrict__ flagp) {
    const bool flg = flagp[0] != 0;
    const int tid = threadIdx.x;
    const int lane = tid & 63, wave = tid >> 6;
    const int m0 = blockIdx.y * 128, n0 = blockIdx.x * 64;
    const int zb = (int)(blockIdx.z >> 3), zh = (int)(blockIdx.z & 7);
    A += (size_t)zb * sAb + (size_t)zh * sAh;
    B += (size_t)zb * sBb + (size_t)zh * sBh;

    __shared__ bf16 As[128][40];
    __shared__ bf16 Bs[64][40];

    const int ar = tid >> 2, ak = (tid & 3) * 8;
    const bf16* Ap0 = A + (size_t)(m0 + ar) * lda + ak;
    const bf16* Ap1 = Ap0 + (size_t)64 * lda;
    const bf16* Bp  = B + (size_t)(n0 + ar) * ldb + ak;

    const int wm = (wave >> 1) * 64, wn = (wave & 1) * 32;
    const int fr = lane & 15, fq = lane >> 4;

    float4v acc[4][2] = {};

    uint4 a0 = *(const uint4*)Ap0;
    uint4 a1 = *(const uint4*)Ap1;
    uint4 b0 = *(const uint4*)Bp;

    for (int k0 = 0; k0 < K; k0 += 32) {
        __syncthreads();
        *(uint4*)&As[ar][ak]      = a0;
        *(uint4*)&As[ar + 64][ak] = a1;
        *(uint4*)&Bs[ar][ak]      = b0;
        if (k0 + 32 < K) {
            a0 = *(const uint4*)(Ap0 + k0 + 32);
            a1 = *(const uint4*)(Ap1 + k0 + 32);
            b0 = *(const uint4*)(Bp + k0 + 32);
        }
        __syncthreads();
        union { uint4 u; short8 s; } ua[4], ub[2];
        #pragma unroll
        for (int i = 0; i < 4; ++i) ua[i].u = *(const uint4*)&As[wm + i * 16 + fr][fq * 8];
        #pragma unroll
        for (int j = 0; j < 2; ++j) ub[j].u = *(const uint4*)&Bs[wn + j * 16 + fr][fq * 8];
        #pragma unroll
        for (int i = 0; i < 4; ++i)
            #pragma unroll
            for (int j = 0; j < 2; ++j)
                acc[i][j] = __builtin_amdgcn_mfma_f32_16x16x32_bf16(ua[i].s, ub[j].s, acc[i][j], 0, 0, 0);
    }

    const long long coff = (long long)zb * sCb + (long long)zh * sCh;
    #pragma unroll
    for (int i = 0; i < 4; ++i) {
        #pragma unroll
        for (int j = 0; j < 2; ++j) {
            #pragma unroll
            for (int r = 0; r < 4; ++r) {
                int m = m0 + wm + i * 16 + fq * 4 + r;
                int n = n0 + wn + j * 16 + fr;
                float v = acc[i][j][r];
                if (EPI == 1) {
                    bf16* C = (bf16*)Cv;
                    if (n < 512) {
                        C[(size_t)m * ldc + n] = __float2bfloat16(v + ldsel(bias, biasoff + n, flg));
                    } else if (n < 1024) {
                        C[(size_t)m * ldc + n] = __float2bfloat16(v);
                    } else {
                        int h = (n >> 6) & 7, d = n & 63, ii = m & 1023, bb = m >> 10;
                        aux[(size_t)(bb * 8 + h) * 65536 + (size_t)d * 1024 + ii] = __float2bfloat16(v);
                    }
                } else if (EPI == 2) {
                    float* C = (float*)Cv;
                    C[(size_t)m * ldc + n] = v + ldsel(bias, biasoff + n, flg) + resid[(size_t)m * ldc + n];
                } else if (EPI == 3) {
                    bf16* C = (bf16*)Cv;
                    float t = v + ldsel(bias, biasoff + n, flg);
                    C[(size_t)m * ldc + n] = __float2bfloat16(0.5f * t * (1.f + erff(t * 0.70710678118f)));
                } else if (EPI == 5) {
                    bf16* C = (bf16*)Cv + coff;
                    C[(size_t)m * ldc + n] = __float2bfloat16(v);
                }
            }
        }
    }
}

// ---- MFMA GEMM 64x64 tile (4 waves, 32x32 per wave) — occupancy variant ----
template<int EPI>
__global__ __launch_bounds__(256) void mgemm64(
    const bf16* __restrict__ A, int lda, long long sAb, long long sAh,
    const bf16* __restrict__ B, int ldb, long long sBb, long long sBh,
    void* __restrict__ Cv, int ldc, long long sCb, long long sCh,
    int K,
    const void* __restrict__ bias, long long biasoff,
    float* __restrict__ resid,
    bf16* __restrict__ aux,
    const int* __restrict__ flagp) {
    const bool flg = flagp[0] != 0;
    const int tid = threadIdx.x;
    const int lane = tid & 63, wave = tid >> 6;
    const int m0 = blockIdx.y * 64, n0 = blockIdx.x * 64;
    const int zb = (int)(blockIdx.z >> 3), zh = (int)(blockIdx.z & 7);
    A += (size_t)zb * sAb + (size_t)zh * sAh;
    B += (size_t)zb * sBb + (size_t)zh * sBh;

    __shared__ bf16 As[64][40];
    __shared__ bf16 Bs[64][40];

    const int ar = tid >> 2, ak = (tid & 3) * 8;
    const bf16* Ap = A + (size_t)(m0 + ar) * lda + ak;
    const bf16* Bp = B + (size_t)(n0 + ar) * ldb + ak;

    const int wm = (wave >> 1) * 32, wn = (wave & 1) * 32;
    const int fr = lane & 15, fq = lane >> 4;

    float4v acc[2][2] = {};

    uint4 a0 = *(const uint4*)Ap;
    uint4 b0 = *(const uint4*)Bp;

    for (int k0 = 0; k0 < K; k0 += 32) {
        __syncthreads();
        *(uint4*)&As[ar][ak] = a0;
        *(uint4*)&Bs[ar][ak] = b0;
        if (k0 + 32 < K) {
            a0 = *(const uint4*)(Ap + k0 + 32);
            b0 = *(const uint4*)(Bp + k0 + 32);
        }
        __syncthreads();
        union { uint4 u; short8 s; } ua[2], ub[2];
        #pragma unroll
        for (int i = 0; i < 2; ++i) ua[i].u = *(const uint4*)&As[wm + i * 16 + fr][fq * 8];
        #pragma unroll
        for (int j = 0; j < 2; ++j) ub[j].u = *(const uint4*)&Bs[wn + j * 16 + fr][fq * 8];
        #pragma unroll
        for (int i = 0; i < 2; ++i)
            #pragma unroll
            for (int j = 0; j < 2; ++j)
                acc[i][j] = __builtin_amdgcn_mfma_f32_16x16x32_bf16(ua[i].s, ub[j].s, acc[i][j], 0, 0, 0);
    }

    const long long coff = (long long)zb * sCb + (long long)zh * sCh;
    #pragma unroll
    for (int i = 0; i < 2; ++i) {
        #pragma unroll
        for (int j = 0; j < 2; ++j) {
            #pragma unroll
            for (int r = 0; r < 4; ++r) {
                int m = m0 + wm + i * 16 + fq * 4 + r;
                int n = n0 + wn + j * 16 + fr;
                float v = acc[i][j][r];
                if (EPI == 1) {
                    bf16* C = (bf16*)Cv;
                    if (n < 512) {
                        C[(size_t)m * ldc + n] = __float2bfloat16(v + ldsel(bias, biasoff + n, flg));
                    } else if (n < 1024) {
                        C[(size_t)m * ldc + n] = __float2bfloat16(v);
                    } else {
                        int h = (n >> 6) & 7, d = n & 63, ii = m & 1023, bb = m >> 10;
                        aux[(size_t)(bb * 8 + h) * 65536 + (size_t)d * 1024 + ii] = __float2bfloat16(v);
                    }
                } else if (EPI == 2) {
                    float* C = (float*)Cv;
                    C[(size_t)m * ldc + n] = v + ldsel(bias, biasoff + n, flg) + resid[(size_t)m * ldc + n];
                } else if (EPI == 5) {
                    bf16* C = (bf16*)Cv + coff;
                    C[(size_t)m * ldc + n] = __float2bfloat16(v);
                }
            }
        }
    }
}

// ---- BD producer: P = (q . wsum)/3 for all 8 heads, rel-shift scatter into
// interleaved Scb[(t-1024)*8 + h]. Register-prefetch across the h-loop.
__global__ __launch_bounds__(512) void bd_kernel(
    const bf16* __restrict__ qkvb, const bf16* __restrict__ wsum,
    bf16* __restrict__ Scb) {
    const int tid = threadIdx.x;
    const int lane = tid & 63, wave = tid >> 6;
    const int n0 = blockIdx.x * 64, m0 = blockIdx.y * 64, b = blockIdx.z;

    __shared__ bf16 Qs[64][72];
    __shared__ bf16 Ws[64][72];

    const int r0 = tid >> 3, c0 = (tid & 7) * 8;
    const bf16* Qp = qkvb + (size_t)(b * 1024 + m0 + r0) * 1536 + c0;
    const bf16* Wp = wsum + (size_t)(b * 1024 + n0 + r0) * 512 + c0;

    const int wm = (wave >> 2) * 32, wn = (wave & 3) * 16;
    const int fr = lane & 15, fq = lane >> 4;

    float4v acc[8][2] = {};

    uint4 qreg = *(const uint4*)Qp;
    uint4 wreg = *(const uint4*)Wp;

    for (int h = 0; h < 8; ++h) {
        __syncthreads();
        *(uint4*)&Qs[r0][c0] = qreg;
        *(uint4*)&Ws[r0][c0] = wreg;
        if (h < 7) {
            qreg = *(const uint4*)(Qp + (h + 1) * 64);
            wreg = *(const uint4*)(Wp + (h + 1) * 64);
        }
        __syncthreads();
        #pragma unroll
        for (int ks = 0; ks < 2; ++ks) {
            union { uint4 u; short8 s; } ua[2], ub;
            #pragma unroll
            for (int i = 0; i < 2; ++i) ua[i].u = *(const uint4*)&Qs[wm + i * 16 + fr][fq * 8 + ks * 32];
            ub.u = *(const uint4*)&Ws[wn + fr][fq * 8 + ks * 32];
            #pragma unroll
            for (int i = 0; i < 2; ++i)
                acc[h][i] = __builtin_amdgcn_mfma_f32_16x16x32_bf16(ua[i].s, ub.s, acc[h][i], 0, 0, 0);
        }
    }

    const size_t pb = (size_t)b * 8388608;
    #pragma unroll
    for (int i = 0; i < 2; ++i) {
        #pragma unroll
        for (int r = 0; r < 4; ++r) {
            int m = m0 + wm + i * 16 + fq * 4 + r;
            int n = n0 + wn + fr;
            int t = m * 1025 + n + 1;
            if (t >= 1024) {
                short8 v;
                #pragma unroll
                for (int h = 0; h < 8; ++h) v[h] = f2bf(acc[h][i][r] * (1.f / 3.f));
                *(short8*)(Scb + pb + (size_t)(t - 1024) * 8) = v;
            }
        }
    }
}

// ---- fused AC + BD + softmax-over-h. 8 waves, 64x64 (i,j) tile. ----
// Register-prefetch across the h-loop; attn written via LDS staging.
__global__ __launch_bounds__(512) void scores_kernel(
    const bf16* __restrict__ qkvb, const bf16* __restrict__ Scb,
    bf16* __restrict__ attn) {
    const int tid = threadIdx.x;
    const int lane = tid & 63, wave = tid >> 6;
    const int j0 = blockIdx.x * 64, i0 = blockIdx.y * 64, b = blockIdx.z;

    __shared__ bf16 Qs[64][72];
    __shared__ bf16 Ks[64][72];

    const int r0 = tid >> 3, c0 = (tid & 7) * 8;
    const bf16* Qp = qkvb + (size_t)(b * 1024 + i0 + r0) * 1536 + c0;
    const bf16* Kp = qkvb + (size_t)(b * 1024 + j0 + r0) * 1536 + 512 + c0;

    const int wm = (wave >> 2) * 32, wn = (wave & 3) * 16;
    const int fr = lane & 15, fq = lane >> 4;

    float4v acc[8][2] = {};

    uint4 qreg = *(const uint4*)Qp;
    uint4 kreg = *(const uint4*)Kp;

    for (int h = 0; h < 8; ++h) {
        __syncthreads();
        *(uint4*)&Qs[r0][c0] = qreg;
        *(uint4*)&Ks[r0][c0] = kreg;
        if (h < 7) {
            qreg = *(const uint4*)(Qp + (h + 1) * 64);
            kreg = *(const uint4*)(Kp + (h + 1) * 64);
        }
        __syncthreads();
        #pragma unroll
        for (int ks = 0; ks < 2; ++ks) {
            union { uint4 u; short8 s; } ua[2], ub;
            #pragma unroll
            for (int i = 0; i < 2; ++i) ua[i].u = *(const uint4*)&Qs[wm + i * 16 + fr][fq * 8 + ks * 32];
            ub.u = *(const uint4*)&Ks[wn + fr][fq * 8 + ks * 32];
            #pragma unroll
            for (int i = 0; i < 2; ++i)
                acc[h][i] = __builtin_amdgcn_mfma_f32_16x16x32_bf16(ua[i].s, ub.s, acc[h][i], 0, 0, 0);
        }
    }

    // pass 1: per-element max + inv-sum over h (bd kept in registers)
    short8 bdv[8];
    float mxs[8], invs[8];
    const size_t pb = (size_t)b * 8388608;
    #pragma unroll
    for (int i = 0; i < 2; ++i) {
        #pragma unroll
        for (int r = 0; r < 4; ++r) {
            const int e = i * 4 + r;
            int gi = i0 + wm + i * 16 + fq * 4 + r;
            int gj = j0 + wn + fr;
            bdv[e] = *(const short8*)(Scb + pb + ((size_t)gi * 1024 + gj) * 8);
            bool diag = (gj == gi + 1);
            float dv[8];
            float mx = -3.4e38f;
            #pragma unroll
            for (int h = 0; h < 8; ++h) {
                float bd = diag ? 0.f : bf2f(bdv[e][h]);
                dv[h] = (acc[h][i][r] + bd) * 0.125f;
                mx = fmaxf(mx, dv[h]);
            }
            float s = 0.f;
            #pragma unroll
            for (int h = 0; h < 8; ++h) s += __expf(dv[h] - mx);
            mxs[e] = mx; invs[e] = 1.f / s;
        }
    }

    // pass 2: per h, stage 64x64 bf16 tile in LDS (Qs reused), write full rows.
    const size_t ab = (size_t)b * 8388608;
    const int orow = tid >> 3, ocol = (tid & 7) * 8;
    #pragma unroll
    for (int h = 0; h < 8; ++h) {
        __syncthreads();
        #pragma unroll
        for (int i = 0; i < 2; ++i) {
            #pragma unroll
            for (int r = 0; r < 4; ++r) {
                const int e = i * 4 + r;
                int gil = wm + i * 16 + fq * 4 + r;
                int gjl = wn + fr;
                int gi = i0 + gil, gj = j0 + gjl;
                float bd = (gj == gi + 1) ? 0.f : bf2f(bdv[e][h]);
                float a = __expf((acc[h][i][r] + bd) * 0.125f - mxs[e]) * invs[e];
                Qs[gil][gjl] = __float2bfloat16(a);
            }
        }
        __syncthreads();
        *(uint4*)(attn + ab + (size_t)h * 1048576 + (size_t)(i0 + orow) * 1024 + j0 + ocol)
            = *(const uint4*)&Qs[orow][ocol];
    }
}

extern "C" void kernel_launch(void* const* d_in, const int* in_sizes, int n_in,
                              void* d_out, int out_size, void* d_ws, size_t ws_size,
                              hipStream_t stream) {
    (void)in_sizes; (void)n_in; (void)out_size; (void)ws_size;
    const void* x_in    = d_in[0];
    const void* r_t     = d_in[1];
    const void* r_c     = d_in[2];
    const void* r_p     = d_in[3];
    const void* bias_pf = d_in[4];
    const void* ln1_g   = d_in[5];
    const void* ln1_b   = d_in[6];
    const void* w_qkv   = d_in[7];
    const void* w_outw  = d_in[8];
    const void* b_out   = d_in[9];
    const void* w_kt    = d_in[10];
    const void* w_kc    = d_in[11];
    const void* w_kp    = d_in[12];
    const void* ln2_g   = d_in[13];
    const void* ln2_b   = d_in[14];
    const void* w_ff1   = d_in[15];
    const void* b_ff1   = d_in[16];
    const void* w_ff2   = d_in[17];
    const void* b_ff2   = d_in[18];

    float* xbuf  = (float*)d_ws;                 // 1M fp32
    bf16* base16 = (bf16*)(xbuf + 1048576);
    bf16* Scb   = base16;                        // 16M (h1 aliases first 4M)
    bf16* h1    = base16;
    bf16* attn  = base16 + 16777216;             // 16M
    bf16* xnb   = attn + 16777216;               // 1M
    bf16* qkvb  = xnb + 1048576;                 // 3M
    bf16* vT    = qkvb + 3145728;                // 1M
    bf16* wsum4 = vT + 1048576;                  // 4M (all 4 layers)
    bf16* rcat  = wsum4 + 4194304;               // 3M
    bf16* arena = rcat + 3145728;                // 15.75M
    int*  flagp = (int*)(arena + 15728640);

    const int LW = 3932160;
    const int WCAT_O = 786432, OUT_O = 1572864, FF1_O = 1835008, FF2_O = 2883584;
    const int QKV_O = 0;

    dim3 blk(256), blk8(512);

    detect_kernel<<<1, 64, 0, stream>>>((const unsigned int*)ln1_g, flagp);
    cast_in<<<512, blk, 0, stream>>>(x_in, xbuf, 131072, flagp);
    rcat_all<<<dim3(512, 3), blk, 0, stream>>>(r_t, r_c, r_p, rcat, flagp);

    prep_weights<<<3840, blk, 0, stream>>>(
        w_qkv, w_kt, w_kc, w_kp, w_outw, w_ff1, w_ff2, arena, flagp);

    // wsum for ALL layers, batched (z = layer): wsum4[l] = rcat @ wcatT[l]^T
    mgemm64<5><<<dim3(8, 32, 4), blk, 0, stream>>>(
        rcat, 1536, 0, 0, arena + WCAT_O, 1536, 0, LW,
        wsum4, 512, 0, 1048576, 1536, nullptr, 0, nullptr, nullptr, flagp);

    for (int l = 0; l < 4; ++l) {
        const bf16* qkvT  = arena + l * LW + QKV_O;
        const bf16* outT  = arena + l * LW + OUT_O;
        const bf16* ff1T  = arena + l * LW + FF1_O;
        const bf16* ff2T  = arena + l * LW + FF2_O;
        const bf16* wsum  = wsum4 + (size_t)l * 1048576;

        // LN1 -> xnb (bf16)
        ln_kernel<<<2048, blk, 0, stream>>>(xbuf, ln1_g, l * 512, ln1_b, l * 512, xnb, flagp);
        // qkv = xnb @ qkvT^T; q += bias_pf; v -> vT
        mgemm64<1><<<dim3(24, 32, 1), blk, 0, stream>>>(
            xnb, 512, 0, 0, qkvT, 512, 0, 0,
            qkvb, 1536, 0, 0, 512, bias_pf, 0, nullptr, vT, flagp);
        // Scb[(t-1024)*8+h] = rel_shift(q . wsum)/3, packed over h
        bd_kernel<<<dim3(16, 16, 2), blk8, 0, stream>>>(qkvb, wsum, Scb);
        // fused AC + BD + softmax -> attn
        scores_kernel<<<dim3(16, 16, 2), blk8, 0, stream>>>(qkvb, Scb, attn);
        // out = attn @ vT^T -> xnb
        mgemm64<5><<<dim3(1, 16, 16), blk, 0, stream>>>(
            attn, 1024, 8388608, 1048576, vT, 1024, 524288, 65536,
            xnb, 512, 524288, 64, 1024, nullptr, 0, nullptr, nullptr, flagp);
        // x = out @ outT^T + b_out + x (fp32)
        mgemm64<2><<<dim3(8, 32, 1), blk, 0, stream>>>(
            xnb, 512, 0, 0, outT, 512, 0, 0,
            xbuf, 512, 0, 0, 512, b_out, (long long)l * 512, xbuf, nullptr, flagp);
        // LN2 -> xnb
        ln_kernel<<<2048, blk, 0, stream>>>(xbuf, ln2_g, l * 512, ln2_b, l * 512, xnb, flagp);
        // h1 = gelu(xnb @ ff1T^T + b_ff1)
        mgemm<3><<<dim3(32, 16, 1), blk, 0, stream>>>(
            xnb, 512, 0, 0, ff1T, 512, 0, 0,
            h1, 2048, 0, 0, 512, b_ff1, (long long)l * 2048, nullptr, nullptr, flagp);
        // x = h1 @ ff2T^T + b_ff2 + x (fp32)
        mgemm64<2><<<dim3(8, 32, 1), blk, 0, stream>>>(
            h1, 2048, 0, 0, ff2T, 2048, 0, 0,
            xbuf, 512, 0, 0, 2048, b_ff2, (long long)l * 512, xbuf, nullptr, flagp);
    }

    // attn (l=3) -> d_out attn region, coalesced
    attn_out<<<8192, blk, 0, stream>>>(attn, d_out, flagp);
    cast_out<<<512, blk, 0, stream>>>(xbuf, d_out, 131072, flagp);
}